// Round 4
// baseline (396.496 us; speedup 1.0000x reference)
//
#include <hip/hip_runtime.h>

#define N_NODES 50000
#define TOPK 32
#define SOFT_DELTA 2e-5f   // boundary-softening gap (GEMM err ~fp32 via 3-tier split)

typedef unsigned long long u64;
typedef unsigned u32;
typedef float f32x16 __attribute__((ext_vector_type(16)));
typedef __bf16 bf16x8 __attribute__((ext_vector_type(8)));

__device__ __forceinline__ float dec(u32 u) {   // inverse order-preserving map
    return __builtin_bit_cast(float, (u & 0x80000000u) ? (u & 0x7FFFFFFFu) : ~u);
}
__device__ __forceinline__ int mbcnt64(u64 m) { // popcount of mask at lanes < mine
    return __builtin_amdgcn_mbcnt_hi((u32)(m >> 32),
           __builtin_amdgcn_mbcnt_lo((u32)m, 0u));
}

// round fp32 to bf16 (half-away), return packed pair + exact residuals
__device__ __forceinline__ u32 s2(float x0, float x1, float& r0, float& r1) {
    const u32 h0 = (__builtin_bit_cast(u32, x0) + 0x8000u) & 0xFFFF0000u;
    const u32 h1 = (__builtin_bit_cast(u32, x1) + 0x8000u) & 0xFFFF0000u;
    r0 = x0 - __builtin_bit_cast(float, h0);    // exact (mantissa tail fits fp32)
    r1 = x1 - __builtin_bit_cast(float, h1);
    return (h0 >> 16) | h1;
}
__device__ __forceinline__ u32 p2(float x0, float x1) {  // rounded pack, no residual
    return (((__builtin_bit_cast(u32, x0) + 0x8000u) & 0xFFFF0000u) >> 16) |
           ((__builtin_bit_cast(u32, x1) + 0x8000u) & 0xFFFF0000u);
}

struct Tri { uint4 h1, h2, h3; };
// 8 consecutive fp32 -> 3 bf16 tiers (x = h1 + h2 + h3 + O(2^-25 x))
__device__ __forceinline__ Tri cvt8(const float4 u, const float4 v, bool deep) {
    Tri t;
    float r0,r1,r2,r3,r4,r5,r6,r7;
    t.h1.x = s2(u.x, u.y, r0, r1);
    t.h1.y = s2(u.z, u.w, r2, r3);
    t.h1.z = s2(v.x, v.y, r4, r5);
    t.h1.w = s2(v.z, v.w, r6, r7);
    float s0,s1,s2_,s3,s4,s5,s6,s7;
    t.h2.x = s2(r0, r1, s0, s1);
    t.h2.y = s2(r2, r3, s2_, s3);
    t.h2.z = s2(r4, r5, s4, s5);
    t.h2.w = s2(r6, r7, s6, s7);
    if (deep) {
        t.h3.x = p2(s0, s1); t.h3.y = p2(s2_, s3);
        t.h3.z = p2(s4, s5); t.h3.w = p2(s6, s7);
    } else {
        t.h3 = make_uint4(0, 0, 0, 0);
    }
    return t;
}

// ---------------------------------------------------------------------------
// Kernel 1: fused GEMM via 3-tier split-bf16 MFMA.
// C = feat @ [W_self ; W_neigh]^T.  128x128 tile, 256 threads (4 waves),
// each wave a 64x64 sub-tile = 2x2 frags of v_mfma_f32_32x32x16_bf16.
// fneigh half (colTile>=2): 6 products (hh,h2h1,h1h2,h2h2,h1h3,h3h1) ->
// error ~4e-6 (fp32-level) so SOFT_DELTA=2e-5 replicates the validated
// fp32 config.  hself half: 3 products (bf16-output tolerance ~0.5).
// BK=32; LDS = 6 x 8KB chunk-major [4][128] uint4 (b128 reads at the
// 4-phase floor, writes 2-way-free).  2 blocks/CU.
// ---------------------------------------------------------------------------
__global__ __launch_bounds__(256, 2) void gemm_kernel(
    const float* __restrict__ feat,     // [N,256]
    const float* __restrict__ Wself,    // [256,256]
    const float* __restrict__ Wneigh,   // [256,256]
    const float* __restrict__ bneigh,   // [256]
    float* __restrict__ hself,          // d_out [N,256]
    float* __restrict__ fneigh)         // ws    [N,256]
{
    __shared__ uint4 LA1[512], LA2[512], LA3[512];
    __shared__ uint4 LB1[512], LB2[512], LB3[512];

    const int tid  = threadIdx.x;
    const int lane = tid & 63;
    const int wave = tid >> 6;
    const int wm   = wave >> 1;        // wave row 0/1 (64 rows each)
    const int wn   = wave & 1;         // wave col 0/1 (64 cols each)
    const int kg   = lane >> 5;        // k-half within a K=16 slice

    const int rowTile = blockIdx.x >> 2;
    const int colTile = blockIdx.x & 3;
    const int row0 = rowTile * 128;
    const float* __restrict__ Wbase = (colTile < 2) ? Wself : Wneigh;
    const int jbase = (colTile & 1) << 7;
    const bool deep = (colTile >= 2);

    // staging map: thread t -> tile row t>>1, k-half (t&1)*16 floats.
    const int srow  = tid >> 1;
    const int shalf = tid & 1;
    int gra = row0 + srow;
    if (gra >= N_NODES) gra = 0;                  // dummy, masked on store
    const float* pa = feat  + (size_t)gra * 256 + shalf * 16;
    const float* pb = Wbase + (size_t)(jbase + srow) * 256 + shalf * 16;
    const int i0 = ((shalf * 2) << 7) + srow;     // chunk-major idx, chunk c0
    const int i1 = i0 + 128;                      // chunk c0+1

    const int rA0 = wm * 64 + (lane & 31);        // frag row base (A)
    const int rB0 = wn * 64 + (lane & 31);        // frag row base (B = out col)

    f32x16 acc[2][2];
#pragma unroll
    for (int i = 0; i < 2; ++i)
#pragma unroll
        for (int j = 0; j < 2; ++j) acc[i][j] = (f32x16)0.f;

    float4 va0, va1, va2, va3, vb0, vb1, vb2, vb3;
    va0 = *(const float4*)(pa);      va1 = *(const float4*)(pa + 4);
    va2 = *(const float4*)(pa + 8);  va3 = *(const float4*)(pa + 12);
    vb0 = *(const float4*)(pb);      vb1 = *(const float4*)(pb + 4);
    vb2 = *(const float4*)(pb + 8);  vb3 = *(const float4*)(pb + 12);

    for (int s = 0; s < 8; ++s) {                 // 8 K-steps of BK=32
        __syncthreads();                          // previous readers done
        {
            const Tri tA0 = cvt8(va0, va1, deep);
            const Tri tA1 = cvt8(va2, va3, deep);
            const Tri tB0 = cvt8(vb0, vb1, deep);
            const Tri tB1 = cvt8(vb2, vb3, deep);
            LA1[i0] = tA0.h1; LA2[i0] = tA0.h2;
            LA1[i1] = tA1.h1; LA2[i1] = tA1.h2;
            LB1[i0] = tB0.h1; LB2[i0] = tB0.h2;
            LB1[i1] = tB1.h1; LB2[i1] = tB1.h2;
            if (deep) {
                LA3[i0] = tA0.h3; LA3[i1] = tA1.h3;
                LB3[i0] = tB0.h3; LB3[i1] = tB1.h3;
            }
        }
        __syncthreads();                          // tile ready

        if (s < 7) {                              // prefetch next K-step
            const int ko = (s + 1) * 32;
            va0 = *(const float4*)(pa + ko);      va1 = *(const float4*)(pa + ko + 4);
            va2 = *(const float4*)(pa + ko + 8);  va3 = *(const float4*)(pa + ko + 12);
            vb0 = *(const float4*)(pb + ko);      vb1 = *(const float4*)(pb + ko + 4);
            vb2 = *(const float4*)(pb + ko + 8);  vb3 = *(const float4*)(pb + ko + 12);
        }

        if (deep) {
#pragma unroll
            for (int ks = 0; ks < 2; ++ks) {      // 2 x K=16 within BK=32
                const int base = ((ks << 1) | kg) << 7;
                bf16x8 a1[2], a2[2], a3[2], b1[2], b2[2], b3[2];
#pragma unroll
                for (int f = 0; f < 2; ++f) {
                    const int ia = base + rA0 + f * 32;
                    const int ib = base + rB0 + f * 32;
                    a1[f] = __builtin_bit_cast(bf16x8, LA1[ia]);
                    a2[f] = __builtin_bit_cast(bf16x8, LA2[ia]);
                    a3[f] = __builtin_bit_cast(bf16x8, LA3[ia]);
                    b1[f] = __builtin_bit_cast(bf16x8, LB1[ib]);
                    b2[f] = __builtin_bit_cast(bf16x8, LB2[ib]);
                    b3[f] = __builtin_bit_cast(bf16x8, LB3[ib]);
                }
#pragma unroll
                for (int i = 0; i < 2; ++i)
#pragma unroll
                    for (int j = 0; j < 2; ++j) {
                        acc[i][j] = __builtin_amdgcn_mfma_f32_32x32x16_bf16(
                            a1[i], b1[j], acc[i][j], 0, 0, 0);
                        acc[i][j] = __builtin_amdgcn_mfma_f32_32x32x16_bf16(
                            a1[i], b2[j], acc[i][j], 0, 0, 0);
                        acc[i][j] = __builtin_amdgcn_mfma_f32_32x32x16_bf16(
                            a2[i], b1[j], acc[i][j], 0, 0, 0);
                        acc[i][j] = __builtin_amdgcn_mfma_f32_32x32x16_bf16(
                            a2[i], b2[j], acc[i][j], 0, 0, 0);
                        acc[i][j] = __builtin_amdgcn_mfma_f32_32x32x16_bf16(
                            a1[i], b3[j], acc[i][j], 0, 0, 0);
                        acc[i][j] = __builtin_amdgcn_mfma_f32_32x32x16_bf16(
                            a3[i], b1[j], acc[i][j], 0, 0, 0);
                    }
            }
        } else {
#pragma unroll
            for (int ks = 0; ks < 2; ++ks) {
                const int base = ((ks << 1) | kg) << 7;
                bf16x8 a1[2], a2[2], b1[2], b2[2];
#pragma unroll
                for (int f = 0; f < 2; ++f) {
                    const int ia = base + rA0 + f * 32;
                    const int ib = base + rB0 + f * 32;
                    a1[f] = __builtin_bit_cast(bf16x8, LA1[ia]);
                    a2[f] = __builtin_bit_cast(bf16x8, LA2[ia]);
                    b1[f] = __builtin_bit_cast(bf16x8, LB1[ib]);
                    b2[f] = __builtin_bit_cast(bf16x8, LB2[ib]);
                }
#pragma unroll
                for (int i = 0; i < 2; ++i)
#pragma unroll
                    for (int j = 0; j < 2; ++j) {
                        acc[i][j] = __builtin_amdgcn_mfma_f32_32x32x16_bf16(
                            a1[i], b1[j], acc[i][j], 0, 0, 0);
                        acc[i][j] = __builtin_amdgcn_mfma_f32_32x32x16_bf16(
                            a1[i], b2[j], acc[i][j], 0, 0, 0);
                        acc[i][j] = __builtin_amdgcn_mfma_f32_32x32x16_bf16(
                            a2[i], b1[j], acc[i][j], 0, 0, 0);
                    }
            }
        }
    }

    // epilogue: D layout col = lane&31, row = (r&3) + 8*(r>>2) + 4*kg.
    // 32 lanes store 128B-contiguous -> no write amplification.
#pragma unroll
    for (int i = 0; i < 2; ++i) {
        const int rbase = row0 + wm * 64 + i * 32 + (kg << 2);
#pragma unroll
        for (int j = 0; j < 2; ++j) {
            const int cg = (colTile << 7) + wn * 64 + j * 32 + (lane & 31);
            float* dst; int c; float badd;
            if (colTile < 2) { dst = hself;  c = cg;       badd = 0.f; }
            else             { dst = fneigh; c = cg - 256; badd = bneigh[cg - 256]; }
#pragma unroll
            for (int r = 0; r < 16; ++r) {
                const int grow = rbase + (r & 3) + ((r >> 2) << 3);
                if (grow < N_NODES)
                    dst[(size_t)grow * 256 + c] = acc[i][j][r] + badd;
            }
        }
    }
}

// ---------------------------------------------------------------------------
// Kernel 2: per-row exact top-32 via 32-step ballot binary search (no
// bpermute storm).  Emits 32 pre-weighted compact entries {col,val} plus a
// softList side entry {c33, 0.5*v33} (0 when not softened).
// One wave per row; grid*4 == N exactly (no early-exit: ballots need all lanes).
// ---------------------------------------------------------------------------
__global__ __launch_bounds__(256) void topk_kernel(
    const float* __restrict__ fneigh,   // [N,256]
    u64*  __restrict__ compact,         // [N*32] {col<<32 | f32bits(w*v)}
    u64*  __restrict__ softList)        // [N]    {col<<32 | f32bits(0.5*v33)} or 0
{
    const int lane = threadIdx.x & 63;
    const int wave = threadIdx.x >> 6;
    const int row  = blockIdx.x * 4 + wave;

    const float4 v4 = ((const float4*)(fneigh + (size_t)row * 256))[lane];
    const float vv[4] = {v4.x, v4.y, v4.z, v4.w};
    u32 key[4];
#pragma unroll
    for (int j = 0; j < 4; ++j) {
        const u32 b = __builtin_bit_cast(u32, vv[j]);
        key[j] = (b & 0x80000000u) ? ~b : (b | 0x80000000u);  // order-preserving
    }

    // T = mapped value of the 32nd largest: max T with count(u >= T) >= 32
    u32 T = 0;
    for (int b = 31; b >= 0; --b) {
        const u32 t2 = T | (1u << b);
        int cnt = 0;
#pragma unroll
        for (int j = 0; j < 4; ++j) cnt += __popcll(__ballot(key[j] >= t2));
        if (cnt >= TOPK) T = t2;
    }

    u64 bgt[4], beq[4];
    int cgt = 0, ceq = 0;
#pragma unroll
    for (int j = 0; j < 4; ++j) {
        bgt[j] = __ballot(key[j] > T);
        beq[j] = __ballot(key[j] == T);
        cgt += __popcll(bgt[j]);
        ceq += __popcll(beq[j]);
    }
    const int r = TOPK - cgt;   // >= 1 (c_gt <= 31 by construction)

    // rank-33 value: T again if ties spill past 32, else max u < T
    u32 m33;
    if (ceq > r) {
        m33 = T;
    } else {
        u32 x = 0;
#pragma unroll
        for (int j = 0; j < 4; ++j) x = max(x, (key[j] < T) ? key[j] : 0u);
#pragma unroll
        for (int off = 32; off >= 1; off >>= 1) x = max(x, (u32)__shfl_xor((int)x, off, 64));
        m33 = x;
    }
    const float v32f = dec(T);
    const float v33f = dec(m33);
    const bool soft = (v32f - v33f) < SOFT_DELTA;

    const int meqsum = mbcnt64(beq[0]) + mbcnt64(beq[1]) +
                       mbcnt64(beq[2]) + mbcnt64(beq[3]);

    int gtbase = 0, selfpre = 0, spillcol = -1;
#pragma unroll
    for (int j = 0; j < 4; ++j) {
        const int col = lane * 4 + j;
        if (key[j] > T) {
            const int pos = gtbase + mbcnt64(bgt[j]);
            compact[(size_t)row * 32 + pos] =
                (((u64)(u32)col) << 32) | (u64)__builtin_bit_cast(u32, vv[j]);
        } else if (key[j] == T) {
            const int eqrank = meqsum + selfpre;   // rank among ties, column order
            if (eqrank < r) {
                const float w = (soft && eqrank == r - 1) ? 0.5f : 1.0f;
                compact[(size_t)row * 32 + (cgt + eqrank)] =
                    (((u64)(u32)col) << 32) | (u64)__builtin_bit_cast(u32, vv[j] * w);
            } else if (eqrank == r) {
                spillcol = col;                    // first unselected tie
            }
            ++selfpre;
        }
        gtbase += __popcll(bgt[j]);
    }

    if (soft) {
        const u64 valbits = (u64)__builtin_bit_cast(u32, 0.5f * v33f);
        if (ceq > r) {
            if (spillcol >= 0)                     // exactly one lane
                softList[row] = (((u64)(u32)spillcol) << 32) | valbits;
        } else {
            int best = 1 << 30;                    // lowest col with u == m33
#pragma unroll
            for (int j = 0; j < 4; ++j) {
                const u64 b33 = __ballot(key[j] == m33);
                if (b33) best = min(best, ((int)__builtin_ctzll(b33)) * 4 + j);
            }
            if (lane == 0)
                softList[row] = (((u64)(u32)best) << 32) | valbits;
        }
    } else if (lane == 0) {
        softList[row] = 0ull;
    }
}

// ---------------------------------------------------------------------------
// Kernel 3: CSR SpMM over compact entries + h_self add.  One wave per dst
// node.  R4: latency-concurrency rework --
//   * 512-thread blocks (8 nodes/block, 6250 blocks) -> 4 blocks/CU = 32
//     waves/CU (was ~17 at 54% occupancy with 256-thread blocks).
//   * no __syncthreads at all: accs[wave] is wave-private, the barriers only
//     coupled wave lifetimes.
//   * 16-edge steps: lane handles edge d+4*(lane>>4), entries 2*(lane&15)
//     and +1 via one 16B u64x2 load -> 4 edges per load inst, 4 loads in
//     flight per step, no MLP=1 remainder path (tail masked by predicated
//     ds_add with clamped shuffle source).
// Lanes 0/16/32/48 additionally apply the rare softList extra for their edge.
// ---------------------------------------------------------------------------
__global__ __launch_bounds__(512) void spmm_kernel(
    const u64* __restrict__ compact,   // [N*32]
    const u64* __restrict__ softList,  // [N]
    const int* __restrict__ indices,   // [E]
    const int* __restrict__ indptr,    // [N+1]
    float* __restrict__ inout)         // d_out: in = h_self, out = result
{
    __shared__ float accs[8][256];

    const int lane = threadIdx.x & 63;
    const int wave = threadIdx.x >> 6;
    const int node = blockIdx.x * 8 + wave;   // grid*8 == N exactly
    float* acc = accs[wave];

    ((float4*)acc)[lane] = make_float4(0.f, 0.f, 0.f, 0.f);  // wave-private slice

    const int start = indptr[node];
    const int deg   = indptr[node + 1] - start;
    const float4 hs = ((const float4*)(inout + (size_t)node * 256))[lane];

    const int eg = lane >> 4;          // edge subgroup 0..3 within a step
    const int e2 = (lane & 15) * 2;    // my entry-pair base within a row
    const bool softlane = (lane & 15) == 0;

    for (int base = 0; base < deg; base += 64) {
        const int n = min(64, deg - base);
        const int myidx = (base + lane < deg) ? indices[start + base + lane] : 0;
        for (int d = 0; d < n; d += 16) {
            int s[4]; int eidx[4]; u64 ea[4], eb[4]; u64 se[4];
#pragma unroll
            for (int k = 0; k < 4; ++k) {
                eidx[k] = d + 4 * k + eg;
                const int src = min(eidx[k], n - 1);   // clamp: garbage masked below
                s[k] = __shfl(myidx, src, 64);
                const u64* p = compact + (size_t)s[k] * 32 + e2;
                ea[k] = p[0];
                eb[k] = p[1];
            }
            if (softlane) {
#pragma unroll
                for (int k = 0; k < 4; ++k) se[k] = softList[s[k]];
            }
#pragma unroll
            for (int k = 0; k < 4; ++k) {
                if (eidx[k] < n) {
                    atomicAdd(&acc[(int)(ea[k] >> 32)],
                              __builtin_bit_cast(float, (u32)ea[k]));
                    atomicAdd(&acc[(int)(eb[k] >> 32)],
                              __builtin_bit_cast(float, (u32)eb[k]));
                    if (softlane) {
                        const u32 vb = (u32)se[k];
                        if (vb)
                            atomicAdd(&acc[(int)(se[k] >> 32)],
                                      __builtin_bit_cast(float, vb));
                    }
                }
            }
        }
    }

    // wave-internal ds ordering (compiler lgkmcnt) -- no barrier needed
    const float4 av = ((const float4*)acc)[lane];
    float4 o;
    o.x = av.x + hs.x;
    o.y = av.y + hs.y;
    o.z = av.z + hs.z;
    o.w = av.w + hs.w;
    ((float4*)(inout + (size_t)node * 256))[lane] = o;
}

// ---------------------------------------------------------------------------
extern "C" void kernel_launch(void* const* d_in, const int* in_sizes, int n_in,
                              void* d_out, int out_size, void* d_ws, size_t ws_size,
                              hipStream_t stream) {
    const float* feat   = (const float*)d_in[0];
    const float* Wself  = (const float*)d_in[1];
    const float* Wneigh = (const float*)d_in[2];
    const float* bneigh = (const float*)d_in[3];
    const int* indices  = (const int*)d_in[4];
    const int* indptr   = (const int*)d_in[5];
    float* out = (float*)d_out;

    char* ws       = (char*)d_ws;
    float* fneigh  = (float*)ws;                                   // 51.2 MB
    u64*  compact  = (u64*)(ws + (size_t)N_NODES * 256 * 4);       // +12.8 MB
    u64*  softList = (u64*)(ws + (size_t)N_NODES * 256 * 4
                               + (size_t)N_NODES * 32 * 8);        // +0.4 MB

    const int rowTiles = (N_NODES + 127) / 128;    // 391
    gemm_kernel<<<dim3(rowTiles * 4), dim3(256), 0, stream>>>(
        feat, Wself, Wneigh, bneigh, out, fneigh);

    const int rowBlocks = N_NODES / 4;             // 12500 (exact)
    topk_kernel<<<dim3(rowBlocks), dim3(256), 0, stream>>>(fneigh, compact, softList);

    const int spmmBlocks = N_NODES / 8;            // 6250 (exact)
    spmm_kernel<<<dim3(spmmBlocks), dim3(512), 0, stream>>>(
        compact, softList, indices, indptr, out);
}

// Round 5
// 394.891 us; speedup vs baseline: 1.0041x; 1.0041x over previous
//
#include <hip/hip_runtime.h>

#define N_NODES 50000
#define TOPK 32
#define SOFT_DELTA 2e-5f   // boundary-softening gap (GEMM err ~fp32 via 3-tier split)

typedef unsigned long long u64;
typedef unsigned u32;
typedef float f32x16 __attribute__((ext_vector_type(16)));
typedef __bf16 bf16x8 __attribute__((ext_vector_type(8)));

__device__ __forceinline__ float dec(u32 u) {   // inverse order-preserving map
    return __builtin_bit_cast(float, (u & 0x80000000u) ? (u & 0x7FFFFFFFu) : ~u);
}
__device__ __forceinline__ int mbcnt64(u64 m) { // popcount of mask at lanes < mine
    return __builtin_amdgcn_mbcnt_hi((u32)(m >> 32),
           __builtin_amdgcn_mbcnt_lo((u32)m, 0u));
}

// 4-byte compact entry: (col << 16) | bf16bits(value).  col in [0,256).
__device__ __forceinline__ u32 enc4(float v, int col) {
    return ((u32)col << 16) |
           ((__builtin_bit_cast(u32, v) + 0x8000u) >> 16);
}

// round fp32 to bf16 (half-away), return packed pair + exact residuals
__device__ __forceinline__ u32 s2(float x0, float x1, float& r0, float& r1) {
    const u32 h0 = (__builtin_bit_cast(u32, x0) + 0x8000u) & 0xFFFF0000u;
    const u32 h1 = (__builtin_bit_cast(u32, x1) + 0x8000u) & 0xFFFF0000u;
    r0 = x0 - __builtin_bit_cast(float, h0);    // exact (mantissa tail fits fp32)
    r1 = x1 - __builtin_bit_cast(float, h1);
    return (h0 >> 16) | h1;
}
__device__ __forceinline__ u32 p2(float x0, float x1) {  // rounded pack, no residual
    return (((__builtin_bit_cast(u32, x0) + 0x8000u) & 0xFFFF0000u) >> 16) |
           ((__builtin_bit_cast(u32, x1) + 0x8000u) & 0xFFFF0000u);
}

struct Tri { uint4 h1, h2, h3; };
// 8 consecutive fp32 -> 3 bf16 tiers (x = h1 + h2 + h3 + O(2^-25 x))
__device__ __forceinline__ Tri cvt8(const float4 u, const float4 v, bool deep) {
    Tri t;
    float r0,r1,r2,r3,r4,r5,r6,r7;
    t.h1.x = s2(u.x, u.y, r0, r1);
    t.h1.y = s2(u.z, u.w, r2, r3);
    t.h1.z = s2(v.x, v.y, r4, r5);
    t.h1.w = s2(v.z, v.w, r6, r7);
    float s0,s1,s2_,s3,s4,s5,s6,s7;
    t.h2.x = s2(r0, r1, s0, s1);
    t.h2.y = s2(r2, r3, s2_, s3);
    t.h2.z = s2(r4, r5, s4, s5);
    t.h2.w = s2(r6, r7, s6, s7);
    if (deep) {
        t.h3.x = p2(s0, s1); t.h3.y = p2(s2_, s3);
        t.h3.z = p2(s4, s5); t.h3.w = p2(s6, s7);
    } else {
        t.h3 = make_uint4(0, 0, 0, 0);
    }
    return t;
}

// ---------------------------------------------------------------------------
// Kernel 1: fused GEMM via 3-tier split-bf16 MFMA.
// C = feat @ [W_self ; W_neigh]^T.  128x128 tile, 256 threads (4 waves),
// each wave a 64x64 sub-tile = 2x2 frags of v_mfma_f32_32x32x16_bf16.
// fneigh half (colTile>=2): 6 products -> error ~4e-6 (fp32-level).
// hself half: 3 products (bf16-output tolerance ~0.5).
// BK=32; LDS = 6 x 8KB chunk-major [4][128] uint4.  2 blocks/CU.
// ---------------------------------------------------------------------------
__global__ __launch_bounds__(256, 2) void gemm_kernel(
    const float* __restrict__ feat,     // [N,256]
    const float* __restrict__ Wself,    // [256,256]
    const float* __restrict__ Wneigh,   // [256,256]
    const float* __restrict__ bneigh,   // [256]
    float* __restrict__ hself,          // d_out [N,256]
    float* __restrict__ fneigh)         // ws    [N,256]
{
    __shared__ uint4 LA1[512], LA2[512], LA3[512];
    __shared__ uint4 LB1[512], LB2[512], LB3[512];

    const int tid  = threadIdx.x;
    const int lane = tid & 63;
    const int wave = tid >> 6;
    const int wm   = wave >> 1;        // wave row 0/1 (64 rows each)
    const int wn   = wave & 1;         // wave col 0/1 (64 cols each)
    const int kg   = lane >> 5;        // k-half within a K=16 slice

    const int rowTile = blockIdx.x >> 2;
    const int colTile = blockIdx.x & 3;
    const int row0 = rowTile * 128;
    const float* __restrict__ Wbase = (colTile < 2) ? Wself : Wneigh;
    const int jbase = (colTile & 1) << 7;
    const bool deep = (colTile >= 2);

    // staging map: thread t -> tile row t>>1, k-half (t&1)*16 floats.
    const int srow  = tid >> 1;
    const int shalf = tid & 1;
    int gra = row0 + srow;
    if (gra >= N_NODES) gra = 0;                  // dummy, masked on store
    const float* pa = feat  + (size_t)gra * 256 + shalf * 16;
    const float* pb = Wbase + (size_t)(jbase + srow) * 256 + shalf * 16;
    const int i0 = ((shalf * 2) << 7) + srow;     // chunk-major idx, chunk c0
    const int i1 = i0 + 128;                      // chunk c0+1

    const int rA0 = wm * 64 + (lane & 31);        // frag row base (A)
    const int rB0 = wn * 64 + (lane & 31);        // frag row base (B = out col)

    f32x16 acc[2][2];
#pragma unroll
    for (int i = 0; i < 2; ++i)
#pragma unroll
        for (int j = 0; j < 2; ++j) acc[i][j] = (f32x16)0.f;

    float4 va0, va1, va2, va3, vb0, vb1, vb2, vb3;
    va0 = *(const float4*)(pa);      va1 = *(const float4*)(pa + 4);
    va2 = *(const float4*)(pa + 8);  va3 = *(const float4*)(pa + 12);
    vb0 = *(const float4*)(pb);      vb1 = *(const float4*)(pb + 4);
    vb2 = *(const float4*)(pb + 8);  vb3 = *(const float4*)(pb + 12);

    for (int s = 0; s < 8; ++s) {                 // 8 K-steps of BK=32
        __syncthreads();                          // previous readers done
        {
            const Tri tA0 = cvt8(va0, va1, deep);
            const Tri tA1 = cvt8(va2, va3, deep);
            const Tri tB0 = cvt8(vb0, vb1, deep);
            const Tri tB1 = cvt8(vb2, vb3, deep);
            LA1[i0] = tA0.h1; LA2[i0] = tA0.h2;
            LA1[i1] = tA1.h1; LA2[i1] = tA1.h2;
            LB1[i0] = tB0.h1; LB2[i0] = tB0.h2;
            LB1[i1] = tB1.h1; LB2[i1] = tB1.h2;
            if (deep) {
                LA3[i0] = tA0.h3; LA3[i1] = tA1.h3;
                LB3[i0] = tB0.h3; LB3[i1] = tB1.h3;
            }
        }
        __syncthreads();                          // tile ready

        if (s < 7) {                              // prefetch next K-step
            const int ko = (s + 1) * 32;
            va0 = *(const float4*)(pa + ko);      va1 = *(const float4*)(pa + ko + 4);
            va2 = *(const float4*)(pa + ko + 8);  va3 = *(const float4*)(pa + ko + 12);
            vb0 = *(const float4*)(pb + ko);      vb1 = *(const float4*)(pb + ko + 4);
            vb2 = *(const float4*)(pb + ko + 8);  vb3 = *(const float4*)(pb + ko + 12);
        }

        if (deep) {
#pragma unroll
            for (int ks = 0; ks < 2; ++ks) {      // 2 x K=16 within BK=32
                const int base = ((ks << 1) | kg) << 7;
                bf16x8 a1[2], a2[2], a3[2], b1[2], b2[2], b3[2];
#pragma unroll
                for (int f = 0; f < 2; ++f) {
                    const int ia = base + rA0 + f * 32;
                    const int ib = base + rB0 + f * 32;
                    a1[f] = __builtin_bit_cast(bf16x8, LA1[ia]);
                    a2[f] = __builtin_bit_cast(bf16x8, LA2[ia]);
                    a3[f] = __builtin_bit_cast(bf16x8, LA3[ia]);
                    b1[f] = __builtin_bit_cast(bf16x8, LB1[ib]);
                    b2[f] = __builtin_bit_cast(bf16x8, LB2[ib]);
                    b3[f] = __builtin_bit_cast(bf16x8, LB3[ib]);
                }
#pragma unroll
                for (int i = 0; i < 2; ++i)
#pragma unroll
                    for (int j = 0; j < 2; ++j) {
                        acc[i][j] = __builtin_amdgcn_mfma_f32_32x32x16_bf16(
                            a1[i], b1[j], acc[i][j], 0, 0, 0);
                        acc[i][j] = __builtin_amdgcn_mfma_f32_32x32x16_bf16(
                            a1[i], b2[j], acc[i][j], 0, 0, 0);
                        acc[i][j] = __builtin_amdgcn_mfma_f32_32x32x16_bf16(
                            a2[i], b1[j], acc[i][j], 0, 0, 0);
                        acc[i][j] = __builtin_amdgcn_mfma_f32_32x32x16_bf16(
                            a2[i], b2[j], acc[i][j], 0, 0, 0);
                        acc[i][j] = __builtin_amdgcn_mfma_f32_32x32x16_bf16(
                            a1[i], b3[j], acc[i][j], 0, 0, 0);
                        acc[i][j] = __builtin_amdgcn_mfma_f32_32x32x16_bf16(
                            a3[i], b1[j], acc[i][j], 0, 0, 0);
                    }
            }
        } else {
#pragma unroll
            for (int ks = 0; ks < 2; ++ks) {
                const int base = ((ks << 1) | kg) << 7;
                bf16x8 a1[2], a2[2], b1[2], b2[2];
#pragma unroll
                for (int f = 0; f < 2; ++f) {
                    const int ia = base + rA0 + f * 32;
                    const int ib = base + rB0 + f * 32;
                    a1[f] = __builtin_bit_cast(bf16x8, LA1[ia]);
                    a2[f] = __builtin_bit_cast(bf16x8, LA2[ia]);
                    b1[f] = __builtin_bit_cast(bf16x8, LB1[ib]);
                    b2[f] = __builtin_bit_cast(bf16x8, LB2[ib]);
                }
#pragma unroll
                for (int i = 0; i < 2; ++i)
#pragma unroll
                    for (int j = 0; j < 2; ++j) {
                        acc[i][j] = __builtin_amdgcn_mfma_f32_32x32x16_bf16(
                            a1[i], b1[j], acc[i][j], 0, 0, 0);
                        acc[i][j] = __builtin_amdgcn_mfma_f32_32x32x16_bf16(
                            a1[i], b2[j], acc[i][j], 0, 0, 0);
                        acc[i][j] = __builtin_amdgcn_mfma_f32_32x32x16_bf16(
                            a2[i], b1[j], acc[i][j], 0, 0, 0);
                    }
            }
        }
    }

    // epilogue: D layout col = lane&31, row = (r&3) + 8*(r>>2) + 4*kg.
    // 32 lanes store 128B-contiguous -> no write amplification.
#pragma unroll
    for (int i = 0; i < 2; ++i) {
        const int rbase = row0 + wm * 64 + i * 32 + (kg << 2);
#pragma unroll
        for (int j = 0; j < 2; ++j) {
            const int cg = (colTile << 7) + wn * 64 + j * 32 + (lane & 31);
            float* dst; int c; float badd;
            if (colTile < 2) { dst = hself;  c = cg;       badd = 0.f; }
            else             { dst = fneigh; c = cg - 256; badd = bneigh[cg - 256]; }
#pragma unroll
            for (int r = 0; r < 16; ++r) {
                const int grow = rbase + (r & 3) + ((r >> 2) << 3);
                if (grow < N_NODES)
                    dst[(size_t)grow * 256 + c] = acc[i][j][r] + badd;
            }
        }
    }
}

// ---------------------------------------------------------------------------
// Kernel 2: per-row exact top-32 via 32-step ballot binary search.
// R5: emits 4-byte compact entries (col<<16 | bf16(w*v)) -> row = 128 B,
// total compact = 6.4 MB (62% of a per-XCD L2).  softList stays u64 (rare).
// One wave per row; grid*4 == N exactly.
// ---------------------------------------------------------------------------
__global__ __launch_bounds__(256) void topk_kernel(
    const float* __restrict__ fneigh,   // [N,256]
    u32*  __restrict__ compact,         // [N*32] (col<<16)|bf16bits(w*v)
    u64*  __restrict__ softList)        // [N]    {col<<32 | f32bits(0.5*v33)} or 0
{
    const int lane = threadIdx.x & 63;
    const int wave = threadIdx.x >> 6;
    const int row  = blockIdx.x * 4 + wave;

    const float4 v4 = ((const float4*)(fneigh + (size_t)row * 256))[lane];
    const float vv[4] = {v4.x, v4.y, v4.z, v4.w};
    u32 key[4];
#pragma unroll
    for (int j = 0; j < 4; ++j) {
        const u32 b = __builtin_bit_cast(u32, vv[j]);
        key[j] = (b & 0x80000000u) ? ~b : (b | 0x80000000u);  // order-preserving
    }

    // T = mapped value of the 32nd largest: max T with count(u >= T) >= 32
    u32 T = 0;
    for (int b = 31; b >= 0; --b) {
        const u32 t2 = T | (1u << b);
        int cnt = 0;
#pragma unroll
        for (int j = 0; j < 4; ++j) cnt += __popcll(__ballot(key[j] >= t2));
        if (cnt >= TOPK) T = t2;
    }

    u64 bgt[4], beq[4];
    int cgt = 0, ceq = 0;
#pragma unroll
    for (int j = 0; j < 4; ++j) {
        bgt[j] = __ballot(key[j] > T);
        beq[j] = __ballot(key[j] == T);
        cgt += __popcll(bgt[j]);
        ceq += __popcll(beq[j]);
    }
    const int r = TOPK - cgt;   // >= 1 (c_gt <= 31 by construction)

    // rank-33 value: T again if ties spill past 32, else max u < T
    u32 m33;
    if (ceq > r) {
        m33 = T;
    } else {
        u32 x = 0;
#pragma unroll
        for (int j = 0; j < 4; ++j) x = max(x, (key[j] < T) ? key[j] : 0u);
#pragma unroll
        for (int off = 32; off >= 1; off >>= 1) x = max(x, (u32)__shfl_xor((int)x, off, 64));
        m33 = x;
    }
    const float v32f = dec(T);
    const float v33f = dec(m33);
    const bool soft = (v32f - v33f) < SOFT_DELTA;

    const int meqsum = mbcnt64(beq[0]) + mbcnt64(beq[1]) +
                       mbcnt64(beq[2]) + mbcnt64(beq[3]);

    int gtbase = 0, selfpre = 0, spillcol = -1;
#pragma unroll
    for (int j = 0; j < 4; ++j) {
        const int col = lane * 4 + j;
        if (key[j] > T) {
            const int pos = gtbase + mbcnt64(bgt[j]);
            compact[(size_t)row * 32 + pos] = enc4(vv[j], col);
        } else if (key[j] == T) {
            const int eqrank = meqsum + selfpre;   // rank among ties, column order
            if (eqrank < r) {
                const float w = (soft && eqrank == r - 1) ? 0.5f : 1.0f;
                compact[(size_t)row * 32 + (cgt + eqrank)] = enc4(vv[j] * w, col);
            } else if (eqrank == r) {
                spillcol = col;                    // first unselected tie
            }
            ++selfpre;
        }
        gtbase += __popcll(bgt[j]);
    }

    if (soft) {
        const u64 valbits = (u64)__builtin_bit_cast(u32, 0.5f * v33f);
        if (ceq > r) {
            if (spillcol >= 0)                     // exactly one lane
                softList[row] = (((u64)(u32)spillcol) << 32) | valbits;
        } else {
            int best = 1 << 30;                    // lowest col with u == m33
#pragma unroll
            for (int j = 0; j < 4; ++j) {
                const u64 b33 = __ballot(key[j] == m33);
                if (b33) best = min(best, ((int)__builtin_ctzll(b33)) * 4 + j);
            }
            if (lane == 0)
                softList[row] = (((u64)(u32)best) << 32) | valbits;
        }
    } else if (lane == 0) {
        softList[row] = 0ull;
    }
}

// ---------------------------------------------------------------------------
// Kernel 3: CSR SpMM over 4-byte compact entries + h_self add.  One wave per
// dst node, 512-thread blocks (8 nodes), no barriers (wave-private acc).
// 8 lanes per edge (uint4 = 4 entries each) -> 8 edges per load inst;
// 16-edge steps with 2 loads in flight.  Tail masked by clamped shuffle
// source + predicated ds_add.  Lanes with (lane&7)==0 apply the rare
// softList extra for their edge.
// ---------------------------------------------------------------------------
__global__ __launch_bounds__(512) void spmm_kernel(
    const u32* __restrict__ compact,   // [N*32] 4B entries
    const u64* __restrict__ softList,  // [N]
    const int* __restrict__ indices,   // [E]
    const int* __restrict__ indptr,    // [N+1]
    float* __restrict__ inout)         // d_out: in = h_self, out = result
{
    __shared__ float accs[8][256];

    const int lane = threadIdx.x & 63;
    const int wave = threadIdx.x >> 6;
    const int node = blockIdx.x * 8 + wave;   // grid*8 == N exactly
    float* acc = accs[wave];

    ((float4*)acc)[lane] = make_float4(0.f, 0.f, 0.f, 0.f);  // wave-private slice

    const int start = indptr[node];
    const int deg   = indptr[node + 1] - start;
    const float4 hs = ((const float4*)(inout + (size_t)node * 256))[lane];

    const int eg = lane >> 3;          // edge subgroup 0..7 within a half-step
    const int e4 = (lane & 7) * 4;     // my 4-entry base within a row
    const bool softlane = (lane & 7) == 0;

    for (int base = 0; base < deg; base += 64) {
        const int n = min(64, deg - base);
        const int myidx = (base + lane < deg) ? indices[start + base + lane] : 0;
        for (int d = 0; d < n; d += 16) {
            const int ei0 = d + eg;
            const int ei1 = d + 8 + eg;
            const int s0 = __shfl(myidx, min(ei0, n - 1), 64);
            const int s1 = __shfl(myidx, min(ei1, n - 1), 64);
            const uint4 la = *(const uint4*)(compact + (size_t)s0 * 32 + e4);
            const uint4 lb = *(const uint4*)(compact + (size_t)s1 * 32 + e4);
            u64 se0 = 0, se1 = 0;
            if (softlane) { se0 = softList[s0]; se1 = softList[s1]; }
            if (ei0 < n) {
                atomicAdd(&acc[la.x >> 16], __builtin_bit_cast(float, la.x << 16));
                atomicAdd(&acc[la.y >> 16], __builtin_bit_cast(float, la.y << 16));
                atomicAdd(&acc[la.z >> 16], __builtin_bit_cast(float, la.z << 16));
                atomicAdd(&acc[la.w >> 16], __builtin_bit_cast(float, la.w << 16));
                if (softlane) {
                    const u32 vb = (u32)se0;
                    if (vb)
                        atomicAdd(&acc[(int)(se0 >> 32)],
                                  __builtin_bit_cast(float, vb));
                }
            }
            if (ei1 < n) {
                atomicAdd(&acc[lb.x >> 16], __builtin_bit_cast(float, lb.x << 16));
                atomicAdd(&acc[lb.y >> 16], __builtin_bit_cast(float, lb.y << 16));
                atomicAdd(&acc[lb.z >> 16], __builtin_bit_cast(float, lb.z << 16));
                atomicAdd(&acc[lb.w >> 16], __builtin_bit_cast(float, lb.w << 16));
                if (softlane) {
                    const u32 vb = (u32)se1;
                    if (vb)
                        atomicAdd(&acc[(int)(se1 >> 32)],
                                  __builtin_bit_cast(float, vb));
                }
            }
        }
    }

    // wave-internal ds ordering (compiler lgkmcnt) -- no barrier needed
    const float4 av = ((const float4*)acc)[lane];
    float4 o;
    o.x = av.x + hs.x;
    o.y = av.y + hs.y;
    o.z = av.z + hs.z;
    o.w = av.w + hs.w;
    ((float4*)(inout + (size_t)node * 256))[lane] = o;
}

// ---------------------------------------------------------------------------
extern "C" void kernel_launch(void* const* d_in, const int* in_sizes, int n_in,
                              void* d_out, int out_size, void* d_ws, size_t ws_size,
                              hipStream_t stream) {
    const float* feat   = (const float*)d_in[0];
    const float* Wself  = (const float*)d_in[1];
    const float* Wneigh = (const float*)d_in[2];
    const float* bneigh = (const float*)d_in[3];
    const int* indices  = (const int*)d_in[4];
    const int* indptr   = (const int*)d_in[5];
    float* out = (float*)d_out;

    char* ws       = (char*)d_ws;
    float* fneigh  = (float*)ws;                                   // 51.2 MB
    u32*  compact  = (u32*)(ws + (size_t)N_NODES * 256 * 4);       // +6.4 MB
    u64*  softList = (u64*)(ws + (size_t)N_NODES * 256 * 4
                               + (size_t)N_NODES * 32 * 4);        // +0.4 MB

    const int rowTiles = (N_NODES + 127) / 128;    // 391
    gemm_kernel<<<dim3(rowTiles * 4), dim3(256), 0, stream>>>(
        feat, Wself, Wneigh, bneigh, out, fneigh);

    const int rowBlocks = N_NODES / 4;             // 12500 (exact)
    topk_kernel<<<dim3(rowBlocks), dim3(256), 0, stream>>>(fneigh, compact, softList);

    const int spmmBlocks = N_NODES / 8;            // 6250 (exact)
    spmm_kernel<<<dim3(spmmBlocks), dim3(512), 0, stream>>>(
        compact, softList, indices, indptr, out);
}

// Round 6
// 300.851 us; speedup vs baseline: 1.3179x; 1.3126x over previous
//
#include <hip/hip_runtime.h>

#define N_NODES 50000
#define TOPK 32
#define SOFT_DELTA 2e-5f   // boundary-softening gap (GEMM err ~fp32 via 3-tier split)

typedef unsigned long long u64;
typedef unsigned u32;
typedef float f32x16 __attribute__((ext_vector_type(16)));
typedef __bf16 bf16x8 __attribute__((ext_vector_type(8)));

__device__ __forceinline__ float dec(u32 u) {   // inverse order-preserving map
    return __builtin_bit_cast(float, (u & 0x80000000u) ? (u & 0x7FFFFFFFu) : ~u);
}
__device__ __forceinline__ int mbcnt64(u64 m) { // popcount of mask at lanes < mine
    return __builtin_amdgcn_mbcnt_hi((u32)(m >> 32),
           __builtin_amdgcn_mbcnt_lo((u32)m, 0u));
}

// 4-byte compact entry: (col << 16) | bf16bits(value).  col in [0,256).
__device__ __forceinline__ u32 enc4(float v, int col) {
    return ((u32)col << 16) |
           ((__builtin_bit_cast(u32, v) + 0x8000u) >> 16);
}

// round fp32 to bf16 (half-away), return packed pair + exact residuals
__device__ __forceinline__ u32 s2(float x0, float x1, float& r0, float& r1) {
    const u32 h0 = (__builtin_bit_cast(u32, x0) + 0x8000u) & 0xFFFF0000u;
    const u32 h1 = (__builtin_bit_cast(u32, x1) + 0x8000u) & 0xFFFF0000u;
    r0 = x0 - __builtin_bit_cast(float, h0);    // exact (mantissa tail fits fp32)
    r1 = x1 - __builtin_bit_cast(float, h1);
    return (h0 >> 16) | h1;
}
__device__ __forceinline__ u32 p2(float x0, float x1) {  // rounded pack, no residual
    return (((__builtin_bit_cast(u32, x0) + 0x8000u) & 0xFFFF0000u) >> 16) |
           ((__builtin_bit_cast(u32, x1) + 0x8000u) & 0xFFFF0000u);
}

struct Tri { uint4 h1, h2, h3; };
// 8 consecutive fp32 -> 3 bf16 tiers (x = h1 + h2 + h3 + O(2^-25 x))
__device__ __forceinline__ Tri cvt8(const float4 u, const float4 v, bool deep) {
    Tri t;
    float r0,r1,r2,r3,r4,r5,r6,r7;
    t.h1.x = s2(u.x, u.y, r0, r1);
    t.h1.y = s2(u.z, u.w, r2, r3);
    t.h1.z = s2(v.x, v.y, r4, r5);
    t.h1.w = s2(v.z, v.w, r6, r7);
    float s0,s1,s2_,s3,s4,s5,s6,s7;
    t.h2.x = s2(r0, r1, s0, s1);
    t.h2.y = s2(r2, r3, s2_, s3);
    t.h2.z = s2(r4, r5, s4, s5);
    t.h2.w = s2(r6, r7, s6, s7);
    if (deep) {
        t.h3.x = p2(s0, s1); t.h3.y = p2(s2_, s3);
        t.h3.z = p2(s4, s5); t.h3.w = p2(s6, s7);
    } else {
        t.h3 = make_uint4(0, 0, 0, 0);
    }
    return t;
}

// ---------------------------------------------------------------------------
// Kernel 1: fused GEMM via 3-tier split-bf16 MFMA.
// C = feat @ [W_self ; W_neigh]^T.  128x128 tile, 256 threads (4 waves),
// each wave a 64x64 sub-tile = 2x2 frags of v_mfma_f32_32x32x16_bf16.
// fneigh half (colTile>=2): 6 products -> error ~4e-6 (fp32-level).
// hself half: 3 products (bf16-output tolerance ~0.5).
// BK=32; LDS = 6 x 8KB chunk-major [4][128] uint4.  2 blocks/CU.
// ---------------------------------------------------------------------------
__global__ __launch_bounds__(256, 2) void gemm_kernel(
    const float* __restrict__ feat,     // [N,256]
    const float* __restrict__ Wself,    // [256,256]
    const float* __restrict__ Wneigh,   // [256,256]
    const float* __restrict__ bneigh,   // [256]
    float* __restrict__ hself,          // d_out [N,256]
    float* __restrict__ fneigh)         // ws    [N,256]
{
    __shared__ uint4 LA1[512], LA2[512], LA3[512];
    __shared__ uint4 LB1[512], LB2[512], LB3[512];

    const int tid  = threadIdx.x;
    const int lane = tid & 63;
    const int wave = tid >> 6;
    const int wm   = wave >> 1;        // wave row 0/1 (64 rows each)
    const int wn   = wave & 1;         // wave col 0/1 (64 cols each)
    const int kg   = lane >> 5;        // k-half within a K=16 slice

    const int rowTile = blockIdx.x >> 2;
    const int colTile = blockIdx.x & 3;
    const int row0 = rowTile * 128;
    const float* __restrict__ Wbase = (colTile < 2) ? Wself : Wneigh;
    const int jbase = (colTile & 1) << 7;
    const bool deep = (colTile >= 2);

    // staging map: thread t -> tile row t>>1, k-half (t&1)*16 floats.
    const int srow  = tid >> 1;
    const int shalf = tid & 1;
    int gra = row0 + srow;
    if (gra >= N_NODES) gra = 0;                  // dummy, masked on store
    const float* pa = feat  + (size_t)gra * 256 + shalf * 16;
    const float* pb = Wbase + (size_t)(jbase + srow) * 256 + shalf * 16;
    const int i0 = ((shalf * 2) << 7) + srow;     // chunk-major idx, chunk c0
    const int i1 = i0 + 128;                      // chunk c0+1

    const int rA0 = wm * 64 + (lane & 31);        // frag row base (A)
    const int rB0 = wn * 64 + (lane & 31);        // frag row base (B = out col)

    f32x16 acc[2][2];
#pragma unroll
    for (int i = 0; i < 2; ++i)
#pragma unroll
        for (int j = 0; j < 2; ++j) acc[i][j] = (f32x16)0.f;

    float4 va0, va1, va2, va3, vb0, vb1, vb2, vb3;
    va0 = *(const float4*)(pa);      va1 = *(const float4*)(pa + 4);
    va2 = *(const float4*)(pa + 8);  va3 = *(const float4*)(pa + 12);
    vb0 = *(const float4*)(pb);      vb1 = *(const float4*)(pb + 4);
    vb2 = *(const float4*)(pb + 8);  vb3 = *(const float4*)(pb + 12);

    for (int s = 0; s < 8; ++s) {                 // 8 K-steps of BK=32
        __syncthreads();                          // previous readers done
        {
            const Tri tA0 = cvt8(va0, va1, deep);
            const Tri tA1 = cvt8(va2, va3, deep);
            const Tri tB0 = cvt8(vb0, vb1, deep);
            const Tri tB1 = cvt8(vb2, vb3, deep);
            LA1[i0] = tA0.h1; LA2[i0] = tA0.h2;
            LA1[i1] = tA1.h1; LA2[i1] = tA1.h2;
            LB1[i0] = tB0.h1; LB2[i0] = tB0.h2;
            LB1[i1] = tB1.h1; LB2[i1] = tB1.h2;
            if (deep) {
                LA3[i0] = tA0.h3; LA3[i1] = tA1.h3;
                LB3[i0] = tB0.h3; LB3[i1] = tB1.h3;
            }
        }
        __syncthreads();                          // tile ready

        if (s < 7) {                              // prefetch next K-step
            const int ko = (s + 1) * 32;
            va0 = *(const float4*)(pa + ko);      va1 = *(const float4*)(pa + ko + 4);
            va2 = *(const float4*)(pa + ko + 8);  va3 = *(const float4*)(pa + ko + 12);
            vb0 = *(const float4*)(pb + ko);      vb1 = *(const float4*)(pb + ko + 4);
            vb2 = *(const float4*)(pb + ko + 8);  vb3 = *(const float4*)(pb + ko + 12);
        }

        if (deep) {
#pragma unroll
            for (int ks = 0; ks < 2; ++ks) {      // 2 x K=16 within BK=32
                const int base = ((ks << 1) | kg) << 7;
                bf16x8 a1[2], a2[2], a3[2], b1[2], b2[2], b3[2];
#pragma unroll
                for (int f = 0; f < 2; ++f) {
                    const int ia = base + rA0 + f * 32;
                    const int ib = base + rB0 + f * 32;
                    a1[f] = __builtin_bit_cast(bf16x8, LA1[ia]);
                    a2[f] = __builtin_bit_cast(bf16x8, LA2[ia]);
                    a3[f] = __builtin_bit_cast(bf16x8, LA3[ia]);
                    b1[f] = __builtin_bit_cast(bf16x8, LB1[ib]);
                    b2[f] = __builtin_bit_cast(bf16x8, LB2[ib]);
                    b3[f] = __builtin_bit_cast(bf16x8, LB3[ib]);
                }
#pragma unroll
                for (int i = 0; i < 2; ++i)
#pragma unroll
                    for (int j = 0; j < 2; ++j) {
                        acc[i][j] = __builtin_amdgcn_mfma_f32_32x32x16_bf16(
                            a1[i], b1[j], acc[i][j], 0, 0, 0);
                        acc[i][j] = __builtin_amdgcn_mfma_f32_32x32x16_bf16(
                            a1[i], b2[j], acc[i][j], 0, 0, 0);
                        acc[i][j] = __builtin_amdgcn_mfma_f32_32x32x16_bf16(
                            a2[i], b1[j], acc[i][j], 0, 0, 0);
                        acc[i][j] = __builtin_amdgcn_mfma_f32_32x32x16_bf16(
                            a2[i], b2[j], acc[i][j], 0, 0, 0);
                        acc[i][j] = __builtin_amdgcn_mfma_f32_32x32x16_bf16(
                            a1[i], b3[j], acc[i][j], 0, 0, 0);
                        acc[i][j] = __builtin_amdgcn_mfma_f32_32x32x16_bf16(
                            a3[i], b1[j], acc[i][j], 0, 0, 0);
                    }
            }
        } else {
#pragma unroll
            for (int ks = 0; ks < 2; ++ks) {
                const int base = ((ks << 1) | kg) << 7;
                bf16x8 a1[2], a2[2], b1[2], b2[2];
#pragma unroll
                for (int f = 0; f < 2; ++f) {
                    const int ia = base + rA0 + f * 32;
                    const int ib = base + rB0 + f * 32;
                    a1[f] = __builtin_bit_cast(bf16x8, LA1[ia]);
                    a2[f] = __builtin_bit_cast(bf16x8, LA2[ia]);
                    b1[f] = __builtin_bit_cast(bf16x8, LB1[ib]);
                    b2[f] = __builtin_bit_cast(bf16x8, LB2[ib]);
                }
#pragma unroll
                for (int i = 0; i < 2; ++i)
#pragma unroll
                    for (int j = 0; j < 2; ++j) {
                        acc[i][j] = __builtin_amdgcn_mfma_f32_32x32x16_bf16(
                            a1[i], b1[j], acc[i][j], 0, 0, 0);
                        acc[i][j] = __builtin_amdgcn_mfma_f32_32x32x16_bf16(
                            a1[i], b2[j], acc[i][j], 0, 0, 0);
                        acc[i][j] = __builtin_amdgcn_mfma_f32_32x32x16_bf16(
                            a2[i], b1[j], acc[i][j], 0, 0, 0);
                    }
            }
        }
    }

    // epilogue: D layout col = lane&31, row = (r&3) + 8*(r>>2) + 4*kg.
    // 32 lanes store 128B-contiguous -> no write amplification.
#pragma unroll
    for (int i = 0; i < 2; ++i) {
        const int rbase = row0 + wm * 64 + i * 32 + (kg << 2);
#pragma unroll
        for (int j = 0; j < 2; ++j) {
            const int cg = (colTile << 7) + wn * 64 + j * 32 + (lane & 31);
            float* dst; int c; float badd;
            if (colTile < 2) { dst = hself;  c = cg;       badd = 0.f; }
            else             { dst = fneigh; c = cg - 256; badd = bneigh[cg - 256]; }
#pragma unroll
            for (int r = 0; r < 16; ++r) {
                const int grow = rbase + (r & 3) + ((r >> 2) << 3);
                if (grow < N_NODES)
                    dst[(size_t)grow * 256 + c] = acc[i][j][r] + badd;
            }
        }
    }
}

// ---------------------------------------------------------------------------
// Kernel 2: per-row exact top-32 via 32-step ballot binary search.
// Emits 4-byte compact entries (col<<16 | bf16(w*v)) -> row = 128 B,
// total compact = 6.4 MB.  softList stays u64 (rare).
// One wave per row; grid*4 == N exactly.
// ---------------------------------------------------------------------------
__global__ __launch_bounds__(256) void topk_kernel(
    const float* __restrict__ fneigh,   // [N,256]
    u32*  __restrict__ compact,         // [N*32] (col<<16)|bf16bits(w*v)
    u64*  __restrict__ softList)        // [N]    {col<<32 | f32bits(0.5*v33)} or 0
{
    const int lane = threadIdx.x & 63;
    const int wave = threadIdx.x >> 6;
    const int row  = blockIdx.x * 4 + wave;

    const float4 v4 = ((const float4*)(fneigh + (size_t)row * 256))[lane];
    const float vv[4] = {v4.x, v4.y, v4.z, v4.w};
    u32 key[4];
#pragma unroll
    for (int j = 0; j < 4; ++j) {
        const u32 b = __builtin_bit_cast(u32, vv[j]);
        key[j] = (b & 0x80000000u) ? ~b : (b | 0x80000000u);  // order-preserving
    }

    // T = mapped value of the 32nd largest: max T with count(u >= T) >= 32
    u32 T = 0;
    for (int b = 31; b >= 0; --b) {
        const u32 t2 = T | (1u << b);
        int cnt = 0;
#pragma unroll
        for (int j = 0; j < 4; ++j) cnt += __popcll(__ballot(key[j] >= t2));
        if (cnt >= TOPK) T = t2;
    }

    u64 bgt[4], beq[4];
    int cgt = 0, ceq = 0;
#pragma unroll
    for (int j = 0; j < 4; ++j) {
        bgt[j] = __ballot(key[j] > T);
        beq[j] = __ballot(key[j] == T);
        cgt += __popcll(bgt[j]);
        ceq += __popcll(beq[j]);
    }
    const int r = TOPK - cgt;   // >= 1 (c_gt <= 31 by construction)

    // rank-33 value: T again if ties spill past 32, else max u < T
    u32 m33;
    if (ceq > r) {
        m33 = T;
    } else {
        u32 x = 0;
#pragma unroll
        for (int j = 0; j < 4; ++j) x = max(x, (key[j] < T) ? key[j] : 0u);
#pragma unroll
        for (int off = 32; off >= 1; off >>= 1) x = max(x, (u32)__shfl_xor((int)x, off, 64));
        m33 = x;
    }
    const float v32f = dec(T);
    const float v33f = dec(m33);
    const bool soft = (v32f - v33f) < SOFT_DELTA;

    const int meqsum = mbcnt64(beq[0]) + mbcnt64(beq[1]) +
                       mbcnt64(beq[2]) + mbcnt64(beq[3]);

    int gtbase = 0, selfpre = 0, spillcol = -1;
#pragma unroll
    for (int j = 0; j < 4; ++j) {
        const int col = lane * 4 + j;
        if (key[j] > T) {
            const int pos = gtbase + mbcnt64(bgt[j]);
            compact[(size_t)row * 32 + pos] = enc4(vv[j], col);
        } else if (key[j] == T) {
            const int eqrank = meqsum + selfpre;   // rank among ties, column order
            if (eqrank < r) {
                const float w = (soft && eqrank == r - 1) ? 0.5f : 1.0f;
                compact[(size_t)row * 32 + (cgt + eqrank)] = enc4(vv[j] * w, col);
            } else if (eqrank == r) {
                spillcol = col;                    // first unselected tie
            }
            ++selfpre;
        }
        gtbase += __popcll(bgt[j]);
    }

    if (soft) {
        const u64 valbits = (u64)__builtin_bit_cast(u32, 0.5f * v33f);
        if (ceq > r) {
            if (spillcol >= 0)                     // exactly one lane
                softList[row] = (((u64)(u32)spillcol) << 32) | valbits;
        } else {
            int best = 1 << 30;                    // lowest col with u == m33
#pragma unroll
            for (int j = 0; j < 4; ++j) {
                const u64 b33 = __ballot(key[j] == m33);
                if (b33) best = min(best, ((int)__builtin_ctzll(b33)) * 4 + j);
            }
            if (lane == 0)
                softList[row] = (((u64)(u32)best) << 32) | valbits;
        }
    } else if (lane == 0) {
        softList[row] = 0ull;
    }
}

// ---------------------------------------------------------------------------
// Kernel 3: CSR SpMM, R6: NO LDS ATOMICS.  One wave per dst node.  Per
// edge-pair: lanes 0-31 hold edge A's 32 entries (lane e = entry e, one
// coalesced u32/lane load = 128B row), lanes 32-63 edge B.  Top-32 cols of
// a row are pairwise distinct -> plain ds_read+add+ds_write per lane has
// ZERO aliasing within an instruction; the two halves use separate 1KB
// accumulators (merged in epilogue).  softList col is rank-33 (provably
// not among the 32) -> also collision-free.  8 pairs batched for MLP.
// Invariant across R2-R5 was the 25.6M random-address LDS-atomic RMWs --
// this removes them entirely.
// ---------------------------------------------------------------------------
__global__ __launch_bounds__(512) void spmm_kernel(
    const u32* __restrict__ compact,   // [N*32] 4B entries
    const u64* __restrict__ softList,  // [N]
    const int* __restrict__ indices,   // [E]
    const int* __restrict__ indptr,    // [N+1]
    float* __restrict__ inout)         // d_out: in = h_self, out = result
{
    __shared__ float accs[8][2][256];  // 16 KB: per-wave, per-half

    const int lane = threadIdx.x & 63;
    const int wave = threadIdx.x >> 6;
    const int node = blockIdx.x * 8 + wave;   // grid*8 == N exactly
    const int half = lane >> 5;        // which edge of the pair
    const int e    = lane & 31;        // my entry index within the row
    float* acc  = accs[wave][half];

    const float4 z4 = make_float4(0.f, 0.f, 0.f, 0.f);
    ((float4*)&accs[wave][0][0])[lane] = z4;   // 64 lanes x 16B = half 0
    ((float4*)&accs[wave][1][0])[lane] = z4;   // half 1

    const int start = indptr[node];
    const int deg   = indptr[node + 1] - start;
    const float4 hs = ((const float4*)(inout + (size_t)node * 256))[lane];

    for (int base = 0; base < deg; base += 64) {
        const int n = min(64, deg - base);
        const int myidx = (base + lane < deg) ? indices[start + base + lane] : 0;
        for (int d = 0; d < n; d += 16) {          // 8 pairs = 16 edges
            int s[8]; bool ok[8]; u32 ent[8];
#pragma unroll
            for (int k = 0; k < 8; ++k) {
                const int ei = d + 2 * k + half;
                ok[k] = ei < n;
                s[k]  = __shfl(myidx, min(ei, n - 1), 64);
                ent[k] = compact[(size_t)s[k] * 32 + e];   // coalesced 128B/edge
            }
            u64 se[8];
            if (e == 0) {                          // lanes 0 & 32: soft extras
#pragma unroll
                for (int k = 0; k < 8; ++k) se[k] = softList[s[k]];
            }
#pragma unroll
            for (int k = 0; k < 8; ++k) {
                const int c = (int)(ent[k] >> 16);
                float v = __builtin_bit_cast(float, ent[k] << 16);
                if (!ok[k]) v = 0.f;               // clamped tail: add 0
                acc[c] += v;                       // non-atomic: cols distinct
                if (e == 0 && ok[k]) {
                    const u32 vb = (u32)se[k];
                    if (vb)
                        acc[(int)(se[k] >> 32)] += __builtin_bit_cast(float, vb);
                }
            }
        }
    }

    // merge halves + h_self; wave-private, compiler lgkmcnt orders ds ops
    const float4 a0 = ((const float4*)&accs[wave][0][0])[lane];
    const float4 a1 = ((const float4*)&accs[wave][1][0])[lane];
    float4 o;
    o.x = a0.x + a1.x + hs.x;
    o.y = a0.y + a1.y + hs.y;
    o.z = a0.z + a1.z + hs.z;
    o.w = a0.w + a1.w + hs.w;
    ((float4*)(inout + (size_t)node * 256))[lane] = o;
}

// ---------------------------------------------------------------------------
extern "C" void kernel_launch(void* const* d_in, const int* in_sizes, int n_in,
                              void* d_out, int out_size, void* d_ws, size_t ws_size,
                              hipStream_t stream) {
    const float* feat   = (const float*)d_in[0];
    const float* Wself  = (const float*)d_in[1];
    const float* Wneigh = (const float*)d_in[2];
    const float* bneigh = (const float*)d_in[3];
    const int* indices  = (const int*)d_in[4];
    const int* indptr   = (const int*)d_in[5];
    float* out = (float*)d_out;

    char* ws       = (char*)d_ws;
    float* fneigh  = (float*)ws;                                   // 51.2 MB
    u32*  compact  = (u32*)(ws + (size_t)N_NODES * 256 * 4);       // +6.4 MB
    u64*  softList = (u64*)(ws + (size_t)N_NODES * 256 * 4
                               + (size_t)N_NODES * 32 * 4);        // +0.4 MB

    const int rowTiles = (N_NODES + 127) / 128;    // 391
    gemm_kernel<<<dim3(rowTiles * 4), dim3(256), 0, stream>>>(
        feat, Wself, Wneigh, bneigh, out, fneigh);

    const int rowBlocks = N_NODES / 4;             // 12500 (exact)
    topk_kernel<<<dim3(rowBlocks), dim3(256), 0, stream>>>(fneigh, compact, softList);

    const int spmmBlocks = N_NODES / 8;            // 6250 (exact)
    spmm_kernel<<<dim3(spmmBlocks), dim3(512), 0, stream>>>(
        compact, softList, indices, indptr, out);
}